// Round 7
// baseline (3784.066 us; speedup 1.0000x reference)
//
#include <hip/hip_runtime.h>
#include <cstddef>

// ---------------------------------------------------------------------------
// SNN forward, feed-forward pipeline. CORRECTNESS CONTRACT: reproduce R3's
// sequential-in-ascending-j fp32 fmaf chain per (t,b,o) (passed, 1.5e-5).
// R10 FACT: fmaf(+0, w, acc) == acc EXACTLY (acc never -0), so skipping
// zero-spike j's is bit-identical.
//
// Ladder: R13=814us L1 (lane=o/reg=t, SALU gate, uncond depth-1 ping-pong,
// 2 waves/SIMD, VALU 55%). R14 gate->replicated VALU: +50% VALU. R15
// t-split: 2x traffic. R17 1 wave/SIMD: latency-exposed. R18 t-in-lane +
// reactive ballot/ctz loads: latency-exposed (36% VALU). R19 SCC-paired
// 2-op gate: SALU count down but SCC coupling serialized -> band GREW.
// Diagnosis: R13's band = SALU->fmac DEPENDENCY coupling at 2 waves/SIMD,
// not SALU count alone.
// R20 = R18's LAYOUT x R13's CONTROL FLOW:
//   - lane=(og,t16), acc a0/a1[16] = 32 VGPR; gate = 6 per-lane VALU
//     (shift/ashr/and x2) serving 32 fmacs; no scalar-chain on fmac path.
//   - loads VERBATIM R13 discipline: unconditional 2-row ping-pong W
//     prefetch depth-1, mask uint4 quads depth-1, readfirstlane, whole-word
//     wave-uniform skip branch only.
//   - ~115 VGPR -> 4 waves/SIMD (2x R13 TLP), launch_bounds(256,4).
//   - epilogue: per-wave LDS transpose, pad 33 (34 was 4-lane/bank -> R18's
//     1.08M conflicts; 33 -> 2/bank free), then verbatim LIF/LI chain.
// Chain order identical: j ascending, skip only whole-zero words, t static.
// ---------------------------------------------------------------------------

#define THREADS 256

// WT offsets (floats): WT1[2048][512], WT2[512][512], WT3[512][256],
// WT4[256][128] (w4 zero-padded 100->128 cols)
#define WOFF1 0
#define WOFF2 1048576
#define WOFF3 1310720
#define WOFF4 1441792
#define WTOT  1474560

__global__ __launch_bounds__(THREADS) void prep_kernel(
    const float* __restrict__ w1, const float* __restrict__ w2,
    const float* __restrict__ w3, const float* __restrict__ w4,
    float* __restrict__ wt)
{
  int idx = blockIdx.x * THREADS + threadIdx.x;
  if (idx >= WTOT) return;
  if (idx < WOFF2) {
    int j = idx >> 9, o = idx & 511;
    wt[idx] = w1[o * 2048 + j];
  } else if (idx < WOFF3) {
    int r = idx - WOFF2, j = r >> 9, o = r & 511;
    wt[idx] = w2[o * 512 + j];
  } else if (idx < WOFF4) {
    int r = idx - WOFF3, j = r >> 8, o = r & 255;
    wt[idx] = w3[o * 512 + j];
  } else {
    int r = idx - WOFF4, j = r >> 7, o = r & 127;
    wt[idx] = (o < 100) ? w4[o * 256 + j] : 0.0f;
  }
}

// Encoder (verbatim R3 arithmetic); writes em[b][j] word = bits over t.
__global__ __launch_bounds__(THREADS) void enc_kernel(
    const float* __restrict__ x, const float* __restrict__ fscale,
    unsigned* __restrict__ em, int b0)
{
  int idx = blockIdx.x * THREADS + threadIdx.x;
  int b = idx >> 11, j = idx & 2047;
  float c = 2.0f * fscale[0] * x[((size_t)(b0 + b) << 11) + j];
  float v = 0.0f;
  unsigned m = 0u;
#pragma unroll
  for (int t = 0; t < 32; ++t) {
    v = v + 0.1f * (c - v);
    unsigned z = ((v - 0.33f) > 0.0f) ? 1u : 0u;
    m |= z << t;
    if (z) v = 0.0f;
  }
  em[idx] = m;
}

// ---------------------------------------------------------------------------
// Sparse-j fused GEMM(+LIF / +LI readout), t-in-lane layout, R13 load flow.
//   mIn: em-format masks [b][J], word = bits over t (wave-uniform per j)
//   WT:  [j][o] pre-transposed weights (rows L2-resident)
// Wave: 64 o's of one b, all 32 t. lane=(og=lane>>4, t16=lane&15); lane
// owns o = obase+og*16+k (k 0..15) at t=t16 (a0) and t16+16 (a1).
// Masks: uint4 quad (4 j) wave-uniform load, depth-1 prefetch, rfl->SGPR.
// W: 2-row ping-pong, UNCONDITIONAL loads (16 floats/lane, 4-way broadcast
// within og-group -> one 256B line per row), depth-1.
// Gate: per-lane (int)(ws<<(31-t16))>>31 & scale, x2 halves. 6 VALU/act-j.
// ---------------------------------------------------------------------------
template <int O, bool FINAL>
__global__ __launch_bounds__(THREADS, 4) void gemm_sparse(
    const unsigned* __restrict__ mIn, const float* __restrict__ WT,
    int J, const float* __restrict__ es,
    unsigned* __restrict__ mOut, float* __restrict__ out, int bbase)
{
  typedef float f16v __attribute__((ext_vector_type(16)));
  constexpr int WPB = O / 64;                // waves per b (8/4/2)
  const int tid = threadIdx.x;
  const int lane = tid & 63, wvid = tid >> 6;
  const int t16 = lane & 15, og = lane >> 4;
  int b, obase;
  if constexpr (WPB == 8) {                  // O=512: 2 blocks per b
    b = blockIdx.x >> 1;
    obase = (blockIdx.x & 1) * 256 + wvid * 64;
  } else if constexpr (WPB == 4) {           // O=256: 1 block per b
    b = blockIdx.x;
    obase = wvid * 64;
  } else {                                   // O=128: 2 b per block
    b = blockIdx.x * 2 + (wvid >> 1);
    obase = (wvid & 1) * 64;
  }
  const float* const wbase = WT + obase + og * 16;  // + j*O at load time
  float scalef = es ? 5.0f * es[0] : 1.0f;   // same expr as R3
  const int scale_i =
      __builtin_amdgcn_readfirstlane(__float_as_int(scalef));
  const int sh0 = 31 - t16, sh1 = 15 - t16;  // per-lane gate shifts

  __shared__ float xp[4][64][33];            // per-wave transpose slab

  float a0[16], a1[16];
#pragma unroll
  for (int k = 0; k < 16; ++k) { a0[k] = 0.0f; a1[k] = 0.0f; }

  const unsigned* mrow = mIn + (size_t)b * J;
  const int Q = J >> 2;                      // mask quads (4 j each)

  auto mload = [&](int q) -> uint4 {
    return *(const uint4*)(mrow + q * 4);    // wave-uniform address
  };
  auto rfl = [&](uint4 mq, unsigned* w) {
    w[0] = (unsigned)__builtin_amdgcn_readfirstlane((int)mq.x);
    w[1] = (unsigned)__builtin_amdgcn_readfirstlane((int)mq.y);
    w[2] = (unsigned)__builtin_amdgcn_readfirstlane((int)mq.z);
    w[3] = (unsigned)__builtin_amdgcn_readfirstlane((int)mq.w);
  };
  auto wload = [&](int g, f16v* wv) {        // UNCONDITIONAL 2-row group
    wv[0] = *(const f16v*)(wbase + (size_t)(g * 2)     * O);
    wv[1] = *(const f16v*)(wbase + (size_t)(g * 2 + 1) * O);
  };
  auto fma2 = [&](const unsigned* w, int s, const f16v* wv) {
#pragma unroll
    for (int jj = 0; jj < 2; ++jj) {
      const unsigned ws = w[s + jj];
      if (ws) {                              // wave-uniform scalar branch
        // per-lane gate: av = bit(ws, t) ? scale : 0  (exact {scale,+0})
        float av0 = __int_as_float(((int)(ws << sh0) >> 31) & scale_i);
        float av1 = __int_as_float(((int)(ws << sh1) >> 31) & scale_i);
#pragma unroll
        for (int k = 0; k < 16; ++k) {
          a0[k] = fmaf(av0, wv[jj][k], a0[k]);
          a1[k] = fmaf(av1, wv[jj][k], a1[k]);
        }
      }
    }
  };

  // R13 control flow: ping-pong 2-row groups, depth-1 W + depth-1 masks.
  unsigned w[4];
  f16v wvA[2], wvB[2];
  {
    uint4 mq0 = mload(0);
    rfl(mq0, w);
    wload(0, wvA);
  }
#pragma unroll 1
  for (int q = 0; q < Q; ++q) {
    uint4 mqN = mload(q + 1 < Q ? q + 1 : Q - 1);  // depth-1 mask prefetch
    wload(2 * q + 1, wvB);                   // unconditional W prefetch
    fma2(w, 0, wvA);                         // j = 4q, 4q+1
    wload(2 * q + 2, wvA);                   // next quad's first group
    fma2(w, 2, wvB);                         // j = 4q+2, 4q+3
    rfl(mqN, w);                             // (tail overrun <=2 rows:
  }                                          //  in-ws, never consumed)

  // ---- epilogue: transpose acc (t-in-lane -> o-in-lane) via LDS, then
  //      verbatim R3 LIF/LI chain per lane's o. One barrier. ----
#pragma unroll
  for (int k = 0; k < 16; ++k) {
    xp[wvid][og * 16 + k][t16]      = a0[k];
    xp[wvid][og * 16 + k][t16 + 16] = a1[k];
  }
  __syncthreads();
  {
    float v = 0.0f, cur = 0.0f;
    unsigned zw = 0u;
#pragma unroll
    for (int t2 = 0; t2 < 32; ++t2) {
      float a = xp[wvid][lane][t2];
      v = v + 0.1f * (cur - v);              // verbatim R3 lif_int / out_li
      if (!FINAL) {
        unsigned z = ((v - 0.33f) > 0.0f) ? 1u : 0u;
        zw |= z << t2;
        if (z) v = 0.0f;
      }
      cur = 0.8f * cur + a;
    }
    if (FINAL) {
      int o = obase + lane;
      if (o < 100) out[(size_t)(bbase + b) * 100 + o] = v;
    } else {
      mOut[(size_t)b * O + obase + lane] = zw;  // em-format for next layer
    }
  }
}

extern "C" void kernel_launch(void* const* d_in, const int* in_sizes, int n_in,
                              void* d_out, int out_size, void* d_ws, size_t ws_size,
                              hipStream_t stream)
{
  const float* x  = (const float*)d_in[0];
  const float* w1 = (const float*)d_in[1];
  const float* w2 = (const float*)d_in[2];
  const float* w3 = (const float*)d_in[3];
  const float* w4 = (const float*)d_in[4];
  const float* fs = (const float*)d_in[5];
  const float* es = (const float*)d_in[6];
  float* out = (float*)d_out;
  (void)in_sizes; (void)n_in; (void)out_size;

  // ws: WT (5.9 MB) + em + s1m + s2m + s3m (all em-format words)
  int Bc = 2048;
  auto need = [](int bc) -> size_t {
    return ((size_t)WTOT + (size_t)bc * (2048 + 512 + 512 + 256)) * 4;
  };
  while (Bc > 64 && need(Bc) > ws_size) Bc >>= 1;

  float* WT = (float*)d_ws;
  unsigned* em  = (unsigned*)(WT + WTOT);
  unsigned* s1m = em  + (size_t)Bc * 2048;
  unsigned* s2m = s1m + (size_t)Bc * 512;
  unsigned* s3m = s2m + (size_t)Bc * 512;

  prep_kernel<<<(WTOT + THREADS - 1) / THREADS, THREADS, 0, stream>>>(
      w1, w2, w3, w4, WT);

  for (int b0 = 0; b0 < 2048; b0 += Bc) {
    enc_kernel<<<(Bc * 2048) / THREADS, THREADS, 0, stream>>>(x, fs, em, b0);
    // L1: J=2048 -> O=512, scale = 5*encoder_scalar (2 blocks per b)
    gemm_sparse<512, false><<<Bc * 2, THREADS, 0, stream>>>(
        em, WT + WOFF1, 2048, es, s1m, nullptr, 0);
    // L2: J=512 -> O=512
    gemm_sparse<512, false><<<Bc * 2, THREADS, 0, stream>>>(
        s1m, WT + WOFF2, 512, nullptr, s2m, nullptr, 0);
    // L3: J=512 -> O=256 (1 block per b)
    gemm_sparse<256, false><<<Bc, THREADS, 0, stream>>>(
        s2m, WT + WOFF3, 512, nullptr, s3m, nullptr, 0);
    // L4 (readout): J=256 -> O=128 (padded), LI epilogue -> out (2 b/block)
    gemm_sparse<128, true><<<Bc / 2, THREADS, 0, stream>>>(
        s3m, WT + WOFF4, 256, nullptr, nullptr, out, b0);
  }
}

// Round 8
// 1244.635 us; speedup vs baseline: 3.0403x; 3.0403x over previous
//
#include <hip/hip_runtime.h>
#include <cstddef>

// ---------------------------------------------------------------------------
// SNN forward, feed-forward pipeline. CORRECTNESS CONTRACT: reproduce R3's
// sequential-in-ascending-j fp32 fmaf chain per (t,b,o) (passed, 1.5e-5).
// R10 FACT: fmaf(+0, w, acc) == acc EXACTLY (acc never -0), so skipping
// zero-spike j's is bit-identical.
//
// Unified model (R13-R20): per act-j/b fmac issue conserved (512 SIMD-cyc);
// R13's wall is BALANCED SALU~=VALU (~55/55%) -> gate re-encodings, NAO
// changes, and occupancy moves all fail. R20 proved t-in-lane kills the
// gate cost (6 VALU/act-j, no SALU) but its 16-lane-broadcast VMEM loads
// are 16x redundant on the vector path (VALU 21%, 2782us). Only LDS
// dedupes broadcast (same-address = free, m136).
// R21 = t-in-lane gating x LDS-staged W:
//   - block = 4 waves = 4 b's x one 64-o slice; W slice SHARED by 4 b's.
//   - 16-row chunks: 256 thr stage 4KB coalesced (1 dwordx4/thr), reg->LDS
//     double-buffer, ONE barrier/chunk. Unique bytes only on the VMEM path.
//   - consume: 4x ds_read_b128/lane (og broadcast; og0/og2 2-way = free).
//   - gate per-lane (6 VALU per act-row, serves 32 fmacs); skip branch
//     wave-uniform (~2 SALU/row -> SALU ~30%, decoupled from VALU).
//   - acc 32 VGPR -> ~90 total -> 4 waves/SIMD (LDS 33KB caps 4 blk/CU).
//   - epilogue: R20's PASS-VERIFIED transpose (pad 33, 0 conflicts).
// j ascending, whole-word skips only, fmaf chain intact -> bit-identical.
// Fallback if regression: revert R13 (1130us) and declare ceiling.
// ---------------------------------------------------------------------------

#define THREADS 256

// WT offsets (floats): WT1[2048][512], WT2[512][512], WT3[512][256],
// WT4[256][128] (w4 zero-padded 100->128 cols)
#define WOFF1 0
#define WOFF2 1048576
#define WOFF3 1310720
#define WOFF4 1441792
#define WTOT  1474560

__global__ __launch_bounds__(THREADS) void prep_kernel(
    const float* __restrict__ w1, const float* __restrict__ w2,
    const float* __restrict__ w3, const float* __restrict__ w4,
    float* __restrict__ wt)
{
  int idx = blockIdx.x * THREADS + threadIdx.x;
  if (idx >= WTOT) return;
  if (idx < WOFF2) {
    int j = idx >> 9, o = idx & 511;
    wt[idx] = w1[o * 2048 + j];
  } else if (idx < WOFF3) {
    int r = idx - WOFF2, j = r >> 9, o = r & 511;
    wt[idx] = w2[o * 512 + j];
  } else if (idx < WOFF4) {
    int r = idx - WOFF3, j = r >> 8, o = r & 255;
    wt[idx] = w3[o * 512 + j];
  } else {
    int r = idx - WOFF4, j = r >> 7, o = r & 127;
    wt[idx] = (o < 100) ? w4[o * 256 + j] : 0.0f;
  }
}

// Encoder (verbatim R3 arithmetic); writes em[b][j] word = bits over t.
__global__ __launch_bounds__(THREADS) void enc_kernel(
    const float* __restrict__ x, const float* __restrict__ fscale,
    unsigned* __restrict__ em, int b0)
{
  int idx = blockIdx.x * THREADS + threadIdx.x;
  int b = idx >> 11, j = idx & 2047;
  float c = 2.0f * fscale[0] * x[((size_t)(b0 + b) << 11) + j];
  float v = 0.0f;
  unsigned m = 0u;
#pragma unroll
  for (int t = 0; t < 32; ++t) {
    v = v + 0.1f * (c - v);
    unsigned z = ((v - 0.33f) > 0.0f) ? 1u : 0u;
    m |= z << t;
    if (z) v = 0.0f;
  }
  em[idx] = m;
}

// ---------------------------------------------------------------------------
// Sparse-j fused GEMM(+LIF / +LI readout), t-in-lane, LDS-staged W.
//   mIn: em-format masks [b][J], word = bits over t (wave-uniform per j)
//   WT:  [j][o] pre-transposed weights
// Block: 4 waves = 4 b's (bgrp*4+wvid) x one o-slice (slice*64).
// lane=(og=lane>>4, t16=lane&15); lane owns o=obase+og*16+k (k 0..15) at
// t=t16 (a0[k]) and t16+16 (a1[k]).
// W: 16-row chunks staged to LDS (coalesced dwordx4/thread, double-buffer,
// 1 barrier/chunk); consumed via ds_read_b128 broadcast.
// Masks: per-wave uint4 quads, chunk-ahead prefetch, readfirstlane.
// ---------------------------------------------------------------------------
template <int O, bool FINAL>
__global__ __launch_bounds__(THREADS, 4) void gemm_sparse(
    const unsigned* __restrict__ mIn, const float* __restrict__ WT,
    int J, const float* __restrict__ es,
    unsigned* __restrict__ mOut, float* __restrict__ out, int bbase)
{
  typedef float f4 __attribute__((ext_vector_type(4)));
  constexpr int NS = O / 64;                 // o-slices per layer
  const int tid = threadIdx.x;
  const int lane = tid & 63, wvid = tid >> 6;
  const int t16 = lane & 15, og = lane >> 4;
  const int bgrp = blockIdx.x / NS, slice = blockIdx.x % NS;
  const int b = bgrp * 4 + wvid;
  const int obase = slice * 64;
  float scalef = es ? 5.0f * es[0] : 1.0f;   // same expr as R3
  const int scale_i =
      __builtin_amdgcn_readfirstlane(__float_as_int(scalef));
  const int sh0 = 31 - t16, sh1 = 15 - t16;  // per-lane gate shifts

  // LDS: stage[2][1024] floats (8KB) overlapped with xp[4][64][33] (33.8KB)
  __shared__ float smem[8448];
  float* const stage0 = smem;                // [buf*1024 + i]
  auto xp = [&](int w, int o, int t) -> float& {
    return smem[w * 2112 + o * 33 + t];
  };

  float a0[16], a1[16];
#pragma unroll
  for (int k = 0; k < 16; ++k) { a0[k] = 0.0f; a1[k] = 0.0f; }

  const unsigned* mrow = mIn + (size_t)b * J;
  const float* const wsrc = WT + obase;      // + row*O + col
  const int NC = J >> 4;                     // 16-row chunks (128/32/32/16)
  const int srow = tid >> 4;                 // staging row 0..15
  const int scol = (tid & 15) * 4;           // staging col

  auto sload = [&](int ch) -> f4 {           // this thread's 4 floats
    return *(const f4*)(wsrc + (size_t)(ch * 16 + srow) * O + scol);
  };
  auto mload4 = [&](int ch, uint4* mq) {     // wave-uniform mask quads
    const unsigned* p = mrow + ch * 16;
#pragma unroll
    for (int q = 0; q < 4; ++q) mq[q] = *(const uint4*)(p + q * 4);
  };
  auto rfl16 = [&](const uint4* mq, unsigned* ws) {
#pragma unroll
    for (int q = 0; q < 4; ++q) {
      ws[q * 4 + 0] = (unsigned)__builtin_amdgcn_readfirstlane((int)mq[q].x);
      ws[q * 4 + 1] = (unsigned)__builtin_amdgcn_readfirstlane((int)mq[q].y);
      ws[q * 4 + 2] = (unsigned)__builtin_amdgcn_readfirstlane((int)mq[q].z);
      ws[q * 4 + 3] = (unsigned)__builtin_amdgcn_readfirstlane((int)mq[q].w);
    }
  };

  unsigned ws[16];
  int cur = 0;
  {                                          // prologue: stage chunk 0
    f4 st = sload(0);
    uint4 mq[4];
    mload4(0, mq);
    *(f4*)&stage0[tid * 4] = st;
    rfl16(mq, ws);
    __syncthreads();
  }
#pragma unroll 1
  for (int ch = 0; ch < NC; ++ch) {
    const int chN = (ch + 1 < NC) ? ch + 1 : ch;   // clamp (stay in-array)
    f4 stN = sload(chN);                     // next chunk -> regs (early)
    uint4 mqN[4];
    mload4(chN, mqN);                        // next masks -> regs (early)
    // ---- consume chunk ch from LDS[cur] ----
#pragma unroll
    for (int r = 0; r < 16; ++r) {
      const unsigned w = ws[r];
      if (w) {                               // wave-uniform scalar branch
        const float* base = &stage0[cur * 1024 + r * 64 + og * 16];
        f4 w0 = *(const f4*)(base);
        f4 w1 = *(const f4*)(base + 4);
        f4 w2 = *(const f4*)(base + 8);
        f4 w3 = *(const f4*)(base + 12);
        // per-lane gate: av = bit(w, t) ? scale : 0  (exact {scale, +0})
        int m0 = ((int)(w << sh0)) >> 31;
        int m1 = ((int)(w << sh1)) >> 31;
        float av0 = __int_as_float(m0 & scale_i);
        float av1 = __int_as_float(m1 & scale_i);
#pragma unroll
        for (int k = 0; k < 4; ++k) {
          a0[k]      = fmaf(av0, w0[k], a0[k]);
          a1[k]      = fmaf(av1, w0[k], a1[k]);
          a0[4 + k]  = fmaf(av0, w1[k], a0[4 + k]);
          a1[4 + k]  = fmaf(av1, w1[k], a1[4 + k]);
          a0[8 + k]  = fmaf(av0, w2[k], a0[8 + k]);
          a1[8 + k]  = fmaf(av1, w2[k], a1[8 + k]);
          a0[12 + k] = fmaf(av0, w3[k], a0[12 + k]);
          a1[12 + k] = fmaf(av1, w3[k], a1[12 + k]);
        }
      }
    }
    // ---- hand off next chunk ----
    *(f4*)&stage0[(cur ^ 1) * 1024 + tid * 4] = stN;  // other buffer: safe
    rfl16(mqN, ws);
    __syncthreads();                         // writes visible; cur drained
    cur ^= 1;
  }

  // ---- epilogue: transpose acc (t-in-lane -> o-in-lane) via LDS (reuses
  //      stage area; all consumes done at last barrier), then verbatim
  //      R3 LIF/LI chain per lane's o. (R20 pass-verified, pad 33.) ----
#pragma unroll
  for (int k = 0; k < 16; ++k) {
    xp(wvid, og * 16 + k, t16)      = a0[k];
    xp(wvid, og * 16 + k, t16 + 16) = a1[k];
  }
  __syncthreads();
  {
    float v = 0.0f, cur2 = 0.0f;
    unsigned zw = 0u;
#pragma unroll
    for (int t2 = 0; t2 < 32; ++t2) {
      float a = xp(wvid, lane, t2);
      v = v + 0.1f * (cur2 - v);             // verbatim R3 lif_int / out_li
      if (!FINAL) {
        unsigned z = ((v - 0.33f) > 0.0f) ? 1u : 0u;
        zw |= z << t2;
        if (z) v = 0.0f;
      }
      cur2 = 0.8f * cur2 + a;
    }
    if (FINAL) {
      int o = obase + lane;
      if (o < 100) out[(size_t)(bbase + b) * 100 + o] = v;
    } else {
      mOut[(size_t)b * O + obase + lane] = zw;  // em-format for next layer
    }
  }
}

extern "C" void kernel_launch(void* const* d_in, const int* in_sizes, int n_in,
                              void* d_out, int out_size, void* d_ws, size_t ws_size,
                              hipStream_t stream)
{
  const float* x  = (const float*)d_in[0];
  const float* w1 = (const float*)d_in[1];
  const float* w2 = (const float*)d_in[2];
  const float* w3 = (const float*)d_in[3];
  const float* w4 = (const float*)d_in[4];
  const float* fs = (const float*)d_in[5];
  const float* es = (const float*)d_in[6];
  float* out = (float*)d_out;
  (void)in_sizes; (void)n_in; (void)out_size;

  // ws: WT (5.9 MB) + em + s1m + s2m + s3m (all em-format words)
  int Bc = 2048;
  auto need = [](int bc) -> size_t {
    return ((size_t)WTOT + (size_t)bc * (2048 + 512 + 512 + 256)) * 4;
  };
  while (Bc > 64 && need(Bc) > ws_size) Bc >>= 1;

  float* WT = (float*)d_ws;
  unsigned* em  = (unsigned*)(WT + WTOT);
  unsigned* s1m = em  + (size_t)Bc * 2048;
  unsigned* s2m = s1m + (size_t)Bc * 512;
  unsigned* s3m = s2m + (size_t)Bc * 512;

  prep_kernel<<<(WTOT + THREADS - 1) / THREADS, THREADS, 0, stream>>>(
      w1, w2, w3, w4, WT);

  for (int b0 = 0; b0 < 2048; b0 += Bc) {
    enc_kernel<<<(Bc * 2048) / THREADS, THREADS, 0, stream>>>(x, fs, em, b0);
    // L1: J=2048 -> O=512 (8 slices), scale = 5*encoder_scalar
    gemm_sparse<512, false><<<(Bc / 4) * 8, THREADS, 0, stream>>>(
        em, WT + WOFF1, 2048, es, s1m, nullptr, 0);
    // L2: J=512 -> O=512 (8 slices)
    gemm_sparse<512, false><<<(Bc / 4) * 8, THREADS, 0, stream>>>(
        s1m, WT + WOFF2, 512, nullptr, s2m, nullptr, 0);
    // L3: J=512 -> O=256 (4 slices)
    gemm_sparse<256, false><<<(Bc / 4) * 4, THREADS, 0, stream>>>(
        s2m, WT + WOFF3, 512, nullptr, s3m, nullptr, 0);
    // L4 (readout): J=256 -> O=128 padded (2 slices), LI epilogue -> out
    gemm_sparse<128, true><<<(Bc / 4) * 2, THREADS, 0, stream>>>(
        s3m, WT + WOFF4, 256, nullptr, nullptr, out, b0);
  }
}